// Round 7
// baseline (122.563 us; speedup 1.0000x reference)
//
#include <hip/hip_runtime.h>

// ---------- helpers ----------
typedef __bf16 bf16x8 __attribute__((ext_vector_type(8)));
typedef float  f32x4  __attribute__((ext_vector_type(4)));
typedef unsigned short u16x8 __attribute__((ext_vector_type(8)));
typedef unsigned int u32;
typedef unsigned long long u64;

static __device__ __forceinline__ unsigned short f32_to_bf16(float f){
  unsigned u = __float_as_uint(f);
  u += 0x7fffu + ((u >> 16) & 1u);          // round-to-nearest-even
  return (unsigned short)(u >> 16);
}
static __device__ __forceinline__ float bf16_to_f32(unsigned short h){
  return __uint_as_float(((unsigned)h) << 16);
}

#define GLOAD_LDS16(g, l)                                                        \
  __builtin_amdgcn_global_load_lds((const __attribute__((address_space(1))) void*)(g), \
                                   (__attribute__((address_space(3))) void*)(l), 16, 0, 0)

// ---------- K0: weight conversion + BN folding ----------
// w1s is stored PRE-SWIZZLED: element (o,c) lands at [o][c ^ ((o&7)<<3)] so that
// conv1's gload_lds-staged LDS tile reads conflict-free (2-way) with a linear DMA dest.
__global__ __launch_bounds__(256) void prep_kernel(
    const float* __restrict__ w1, const float* __restrict__ w2,
    const float* __restrict__ b1, const float* __restrict__ g1, const float* __restrict__ be1,
    const float* __restrict__ m1, const float* __restrict__ v1,
    const float* __restrict__ b2, const float* __restrict__ g2, const float* __restrict__ be2,
    const float* __restrict__ m2, const float* __restrict__ v2,
    unsigned short* __restrict__ w1s, unsigned short* __restrict__ w2b,
    float* __restrict__ sc1, float* __restrict__ sh1,
    float* __restrict__ sc2, float* __restrict__ sh2)
{
  int i = blockIdx.x * 256 + threadIdx.x;
  int stride = gridDim.x * 256;
  for (int k = i; k < 512 * 2048; k += stride){
    int o = k >> 11, c = k & 2047;
    w1s[(o << 11) | (c ^ ((o & 7) << 3))] = f32_to_bf16(w1[k]);
  }
  for (int k = i; k < 256 * 512;  k += stride) w2b[k] = f32_to_bf16(w2[k]);
  if (i < 512){
    float s = g1[i] * rsqrtf(v1[i] + 1e-5f);
    sc1[i] = s;
    sh1[i] = (b1[i] - m1[i]) * s + be1[i];   // conv bias folded into BN shift
  } else if (i - 512 < 256){
    int o = i - 512;
    float s = g2[o] * rsqrtf(v2[o] + 1e-5f);
    sc2[o] = s;
    sh2[o] = (b2[o] - m2[o]) * s + be2[o];
  }
}

// ---------- K1: conv1 full map (m97-style): Zt[b*4096+p][512] = (W1.F)^T ----------
// 128p x 128o tile, BK=64, 4 waves (2x2 of 64x64), grid 512 = 2 blocks/CU.
// Latency hiding via block-level TLP (m114), not intra-block choreography.
// A (features f32->bf16): reg-staged, swizzle key f(p)=(p^(p>>3))&7 (2-way both sides).
// B (weights): gload_lds direct from PRE-SWIZZLED w1s, linear LDS dest.
__global__ __launch_bounds__(256, 2) void conv1_kernel(
    const unsigned short* __restrict__ w1s,   // [512][2048] bf16, pre-swizzled
    const float* __restrict__ feat,           // [4][2048][4096] f32
    unsigned short* __restrict__ zt)          // [4*4096][512] bf16
{
  __shared__ unsigned short lds[2][128 * 64]; // [0]=A [p][c] swz ; [1]=B [o][c'] ; 32KB
  int t = threadIdx.x, l = t & 63, wid = t >> 6;
  int wr = wid >> 1, wc = wid & 1;

  int lid = ((blockIdx.x & 7) << 6) | (blockIdx.x >> 3);  // XCD-contiguous
  int nt = lid >> 7;            // 0..3  (same-nt blocks share weight slice per XCD)
  int mt = lid & 127;           // 0..127
  int bb = mt >> 5;
  int p0 = (mt & 31) << 7;
  int o0 = nt << 7;

  // A staging: thread loads c-rows c4..c4+3, f32x4 along p at p4 (+64*pp)
  int c4 = (t >> 4) << 2;       // 0..60
  int p4 = (t & 15) << 2;       // 0..60
  const float* fBase = feat + ((size_t)(bb * 2048 + c4)) * 4096 + p0 + p4;

  // B staging (wave-uniform base + lane*16 dest, as gload_lds requires)
  const unsigned short* bBase = w1s + ((size_t)(o0 + (t >> 3))) * 2048 + (t & 7) * 8;
  unsigned short* bDst = (unsigned short*)lds[1] + (t >> 3) * 64 + (t & 7) * 8;

  f32x4 acc[4][4];
  f32x4 z4 = {0.f, 0.f, 0.f, 0.f};
  #pragma unroll
  for (int m = 0; m < 4; ++m)
    #pragma unroll
    for (int n = 0; n < 4; ++n) acc[m][n] = z4;

  f32x4 rA[2][4];

#define LOAD_A(kt) do {                                                     \
    _Pragma("unroll")                                                       \
    for (int pp = 0; pp < 2; ++pp)                                          \
      _Pragma("unroll")                                                     \
      for (int j = 0; j < 4; ++j)                                           \
        rA[pp][j] = *(const f32x4*)(fBase + (size_t)((kt) + j) * 4096 + pp * 64); \
  } while (0)

#define WRITE_A() do {                                                      \
    _Pragma("unroll")                                                       \
    for (int pp = 0; pp < 2; ++pp)                                          \
      _Pragma("unroll")                                                     \
      for (int i = 0; i < 4; ++i){                                          \
        int p_ = p4 + pp * 64 + i;                                          \
        int f_ = (p_ ^ (p_ >> 3)) & 7;                                      \
        u32 lo_ = ((u32)f32_to_bf16(rA[pp][0][i])) | (((u32)f32_to_bf16(rA[pp][1][i])) << 16); \
        u32 hi_ = ((u32)f32_to_bf16(rA[pp][2][i])) | (((u32)f32_to_bf16(rA[pp][3][i])) << 16); \
        u64 v_ = ((u64)hi_ << 32) | lo_;                                    \
        *(u64*)((char*)lds[0] + p_ * 128 + ((c4 * 2) ^ (f_ << 4))) = v_;    \
      }                                                                     \
  } while (0)

#define MFMA_ALL() do {                                                     \
    _Pragma("unroll")                                                       \
    for (int ks = 0; ks < 2; ++ks){                                         \
      bf16x8 af_[4], bf_[4];                                                \
      int cb_ = ks * 64 + (l >> 4) * 16;                                    \
      _Pragma("unroll")                                                     \
      for (int m = 0; m < 4; ++m){                                          \
        int p_ = wr * 64 + m * 16 + (l & 15);                               \
        int f_ = (p_ ^ (p_ >> 3)) & 7;                                      \
        af_[m] = *(const bf16x8*)((const char*)lds[0] + p_ * 128 + (cb_ ^ (f_ << 4))); \
      }                                                                     \
      _Pragma("unroll")                                                     \
      for (int n = 0; n < 4; ++n){                                          \
        int o_ = wc * 64 + n * 16 + (l & 15);                               \
        bf_[n] = *(const bf16x8*)((const char*)lds[1] + o_ * 128 + (cb_ ^ ((o_ & 7) << 4))); \
      }                                                                     \
      _Pragma("unroll")                                                     \
      for (int m = 0; m < 4; ++m)                                           \
        _Pragma("unroll")                                                   \
        for (int n = 0; n < 4; ++n)                                         \
          acc[m][n] = __builtin_amdgcn_mfma_f32_16x16x32_bf16(af_[m], bf_[n], acc[m][n], 0, 0, 0); \
    }                                                                       \
  } while (0)

  LOAD_A(0);
  for (int kt = 0; kt < 2048; kt += 64){
    WRITE_A();                                  // compiler waits rA's vmcnt
    #pragma unroll
    for (int i = 0; i < 4; ++i)
      GLOAD_LDS16(bBase + (size_t)i * (32 * 2048) + kt, bDst + i * (32 * 64));
    __syncthreads();                            // drains B-DMA + A-writes (vmcnt0+lgkm0)
    if (kt < 1984) LOAD_A(kt + 64);             // prefetch: stays in flight across MFMA+barrier
    MFMA_ALL();
    asm volatile("s_waitcnt lgkmcnt(0)" ::: "memory");  // reads retired; do NOT drain vmcnt
    __builtin_amdgcn_s_barrier();
  }

  // epilogue: stage [128p][128o] transposed into lds (32KB) as p-rows of 256B
  #pragma unroll
  for (int m = 0; m < 4; ++m){
    #pragma unroll
    for (int n = 0; n < 4; ++n){
      int o_c = wc * 64 + n * 16 + (l & 15);
      #pragma unroll
      for (int r = 0; r < 4; ++r){
        int p_ = wr * 64 + m * 16 + (l >> 4) * 4 + r;
        *(unsigned short*)((char*)lds + p_ * 256 + ((o_c * 2) ^ ((p_ & 7) << 4))) =
            f32_to_bf16(acc[m][n][r]);
      }
    }
  }
  __syncthreads();
  {
    int p = t >> 1, half = t & 1;
    size_t dstb = ((size_t)(bb * 4096 + p0 + p)) * 1024 + (size_t)nt * 256 + half * 128;
    int swz = (p & 7) << 4;
    #pragma unroll
    for (int q = 0; q < 8; ++q){
      int y = ((half * 8 + q) * 16) ^ swz;
      f32x4 v = *(const f32x4*)((char*)lds + p * 256 + y);
      *(f32x4*)((char*)zt + dstb + q * 16) = v;
    }
  }
#undef LOAD_A
#undef WRITE_A
#undef MFMA_ALL
}

// ---------- K2: ROI gather on Zt (512 ch) + BN1 + ReLU -> h1 bf16 [6272][512] ----------
__global__ __launch_bounds__(256) void roi_gather_kernel(
    const unsigned short* __restrict__ zt, const float* __restrict__ boxes,
    const float* __restrict__ sc1, const float* __restrict__ sh1,
    unsigned short* __restrict__ h1)
{
  int ky = blockIdx.x, roi = blockIdx.y;
  __shared__ int   sIdx[16][8];
  __shared__ float sW[16][8];
  int t = threadIdx.x;

  int   b   = (int)boxes[roi * 5 + 0];
  float bx1 = boxes[roi * 5 + 1], by1 = boxes[roi * 5 + 2];
  float bx2 = boxes[roi * 5 + 3], by2 = boxes[roi * 5 + 4];
  float rw = fmaxf(bx2 - bx1, 1.f), rh = fmaxf(by2 - by1, 1.f);
  float bw = rw * (1.f / 7.f), bh = rh * (1.f / 7.f);

  if (t < 28){
    int kx = t >> 2, s = t & 3;
    int sy = s >> 1, sx = s & 1;
    float yy = by1 + ((float)ky + ((float)sy + 0.5f) * 0.5f) * bh;
    float xx = bx1 + ((float)kx + ((float)sx + 0.5f) * 0.5f) * bw;
    bool vy = (yy >= -1.f) && (yy <= 64.f);
    bool vx = (xx >= -1.f) && (xx <= 64.f);
    float yc = fminf(fmaxf(yy, 0.f), 63.f);
    float xc = fminf(fmaxf(xx, 0.f), 63.f);
    int iy0 = (int)yc, ix0 = (int)xc;
    int iy1 = min(iy0 + 1, 63), ix1 = min(ix0 + 1, 63);
    float fy = yc - (float)iy0, fx = xc - (float)ix0;
    float v = (vy && vx) ? 0.25f : 0.f;
    float wy0 = 1.f - fy, wx0 = 1.f - fx;
    sIdx[s * 4 + 0][kx] = iy0 * 64 + ix0;  sW[s * 4 + 0][kx] = wy0 * wx0 * v;
    sIdx[s * 4 + 1][kx] = iy0 * 64 + ix1;  sW[s * 4 + 1][kx] = wy0 * fx  * v;
    sIdx[s * 4 + 2][kx] = iy1 * 64 + ix0;  sW[s * 4 + 2][kx] = fy  * wx0 * v;
    sIdx[s * 4 + 3][kx] = iy1 * 64 + ix1;  sW[s * 4 + 3][kx] = fy  * fx  * v;
  }
  __syncthreads();

  int w = t >> 6, l = t & 63;
  f32x4 s0 = *(const f32x4*)(sc1 + l * 8);
  f32x4 s1 = *(const f32x4*)(sc1 + l * 8 + 4);
  f32x4 h0 = *(const f32x4*)(sh1 + l * 8);
  f32x4 hh = *(const f32x4*)(sh1 + l * 8 + 4);
  const unsigned short* zb = zt + ((size_t)b * 4096) * 512 + l * 8;

  for (int kx = w; kx < 7; kx += 4){
    float a[8];
    #pragma unroll
    for (int j = 0; j < 8; ++j) a[j] = 0.f;
    #pragma unroll
    for (int i = 0; i < 16; ++i){
      int idx = sIdx[i][kx];
      float wt = sW[i][kx];
      u16x8 v = *(const u16x8*)(zb + (size_t)idx * 512);
      #pragma unroll
      for (int j = 0; j < 8; ++j) a[j] += wt * bf16_to_f32(v[j]);
    }
    u16x8 o;
    #pragma unroll
    for (int j = 0; j < 4; ++j){
      float v0 = fmaxf(a[j] * s0[j] + h0[j], 0.f);
      float v1 = fmaxf(a[j + 4] * s1[j] + hh[j], 0.f);
      o[j] = f32_to_bf16(v0);
      o[j + 4] = f32_to_bf16(v1);
    }
    *(u16x8*)(h1 + ((size_t)(roi * 49 + ky * 7 + kx)) * 512 + l * 8) = o;
  }
}

// ---------- K3: bf16 GEMM, B-transposed input, fused scale/shift + ReLU ----------
template<int BM, int BN>
__global__ __launch_bounds__(256) void gemm_bt_relu(
    const unsigned short* __restrict__ A, const unsigned short* __restrict__ Bt,
    const float* __restrict__ scale, const float* __restrict__ shift,
    unsigned short* __restrict__ C, int M, int N, int K)
{
  constexpr int BK = 64;
  constexpr int FM = BM / 32;
  constexpr int FN = BN / 32;
  __shared__ unsigned short lds_a[BM * BK];
  __shared__ unsigned short lds_b[BN * BK];
  int t = threadIdx.x;
  int l = t & 63, wid = t >> 6;
  int wr = wid >> 1, wc = wid & 1;
  int m0 = blockIdx.y * BM, n0 = blockIdx.x * BN;

  f32x4 acc[FM][FN];
  f32x4 z = {0.f, 0.f, 0.f, 0.f};
  #pragma unroll
  for (int m = 0; m < FM; ++m)
    #pragma unroll
    for (int n = 0; n < FN; ++n) acc[m][n] = z;

  const unsigned short* Ab = A  + (size_t)m0 * K;
  const unsigned short* Bb = Bt + (size_t)n0 * K;

  for (int kt = 0; kt < K; kt += BK){
    #pragma unroll
    for (int r = 0; r < BM / 32; ++r){
      int row = r * 32 + (t >> 3);
      GLOAD_LDS16(Ab + (size_t)row * K + kt + (t & 7) * 8,
                  lds_a + row * BK + (t & 7) * 8);
    }
    #pragma unroll
    for (int r = 0; r < BN / 32; ++r){
      int row = r * 32 + (t >> 3);
      GLOAD_LDS16(Bb + (size_t)row * K + kt + (t & 7) * 8,
                  lds_b + row * BK + (t & 7) * 8);
    }
    __syncthreads();
    #pragma unroll
    for (int ks = 0; ks < 2; ++ks){
      bf16x8 af[FM], bfr[FN];
      #pragma unroll
      for (int m = 0; m < FM; ++m)
        af[m] = *reinterpret_cast<const bf16x8*>(
            lds_a + (wr * (BM / 2) + m * 16 + (l & 15)) * BK + ks * 32 + (l >> 4) * 8);
      #pragma unroll
      for (int n = 0; n < FN; ++n)
        bfr[n] = *reinterpret_cast<const bf16x8*>(
            lds_b + (wc * (BN / 2) + n * 16 + (l & 15)) * BK + ks * 32 + (l >> 4) * 8);
      #pragma unroll
      for (int m = 0; m < FM; ++m)
        #pragma unroll
        for (int n = 0; n < FN; ++n)
          acc[m][n] = __builtin_amdgcn_mfma_f32_16x16x32_bf16(af[m], bfr[n], acc[m][n], 0, 0, 0);
    }
    __syncthreads();
  }

  #pragma unroll
  for (int m = 0; m < FM; ++m){
    int gr = m0 + wr * (BM / 2) + m * 16 + (l >> 4) * 4;
    #pragma unroll
    for (int n = 0; n < FN; ++n){
      int gc = n0 + wc * (BN / 2) + n * 16 + (l & 15);
      float sc = scale[gc], sh = shift[gc];
      #pragma unroll
      for (int r = 0; r < 4; ++r){
        float v = acc[m][n][r] * sc + sh;
        v = fmaxf(v, 0.f);
        C[(size_t)(gr + r) * N + gc] = f32_to_bf16(v);
      }
    }
  }
}

// ---------- K4: mean over 49 bins -> out f32 [128][256] ----------
__global__ __launch_bounds__(256) void reduce_kernel(
    const unsigned short* __restrict__ h2, float* __restrict__ out)
{
  int n = blockIdx.x, o = threadIdx.x;
  const unsigned short* p = h2 + (size_t)n * 49 * 256 + o;
  float s = 0.f;
  for (int j = 0; j < 49; ++j) s += bf16_to_f32(p[j * 256]);
  out[n * 256 + o] = s * (1.f / 49.f);
}

// ---------- launch ----------
extern "C" void kernel_launch(void* const* d_in, const int* in_sizes, int n_in,
                              void* d_out, int out_size, void* d_ws, size_t ws_size,
                              hipStream_t stream)
{
  const float* feat  = (const float*)d_in[0];
  const float* boxes = (const float*)d_in[1];
  const float* w1  = (const float*)d_in[2];
  const float* b1  = (const float*)d_in[3];
  const float* g1  = (const float*)d_in[4];
  const float* be1 = (const float*)d_in[5];
  const float* m1  = (const float*)d_in[6];
  const float* v1  = (const float*)d_in[7];
  const float* w2  = (const float*)d_in[8];
  const float* b2  = (const float*)d_in[9];
  const float* g2  = (const float*)d_in[10];
  const float* be2 = (const float*)d_in[11];
  const float* m2  = (const float*)d_in[12];
  const float* v2  = (const float*)d_in[13];
  float* out = (float*)d_out;

  char* ws = (char*)d_ws;
  unsigned short* w1s = (unsigned short*)(ws);                         // 2 MB (pre-swizzled)
  unsigned short* w2b = (unsigned short*)(ws + (2u << 20));            // 256 KB
  float* sc1 = (float*)(ws + (2u << 20) + (256u << 10));
  float* sh1 = sc1 + 512;
  float* sc2 = sh1 + 512;
  float* sh2 = sc2 + 256;
  unsigned short* zt = (unsigned short*)(ws + (4u  << 20));            // 16.8 MB
  unsigned short* h1 = (unsigned short*)(ws + (24u << 20));            // 6.4 MB
  unsigned short* h2 = (unsigned short*)(ws + (32u << 20));            // 3.2 MB

  hipLaunchKernelGGL(prep_kernel, dim3(256), dim3(256), 0, stream,
                     w1, w2, b1, g1, be1, m1, v1, b2, g2, be2, m2, v2,
                     w1s, w2b, sc1, sh1, sc2, sh2);
  hipLaunchKernelGGL(conv1_kernel, dim3(512), dim3(256), 0, stream,
                     w1s, feat, zt);
  hipLaunchKernelGGL(roi_gather_kernel, dim3(7, 128), dim3(256), 0, stream,
                     zt, boxes, sc1, sh1, h1);
  hipLaunchKernelGGL(HIP_KERNEL_NAME(gemm_bt_relu<128, 64>),
                     dim3(256 / 64, 6272 / 128), dim3(256), 0, stream,
                     h1, w2b, sc2, sh2, h2, 6272, 256, 512);
  hipLaunchKernelGGL(reduce_kernel, dim3(128), dim3(256), 0, stream, h2, out);
}

// Round 8
// 92.565 us; speedup vs baseline: 1.3241x; 1.3241x over previous
//
#include <hip/hip_runtime.h>

// ---------- helpers ----------
typedef __bf16 bf16x8 __attribute__((ext_vector_type(8)));
typedef float  f32x4  __attribute__((ext_vector_type(4)));
typedef float  f32x16 __attribute__((ext_vector_type(16)));
typedef unsigned short u16x8 __attribute__((ext_vector_type(8)));
typedef unsigned int u32;
typedef unsigned long long u64;

static __device__ __forceinline__ unsigned short f32_to_bf16(float f){
  unsigned u = __float_as_uint(f);
  u += 0x7fffu + ((u >> 16) & 1u);          // round-to-nearest-even
  return (unsigned short)(u >> 16);
}
static __device__ __forceinline__ float bf16_to_f32(unsigned short h){
  return __uint_as_float(((unsigned)h) << 16);
}

#define GLOAD_LDS16(g, l)                                                        \
  __builtin_amdgcn_global_load_lds((const __attribute__((address_space(1))) void*)(g), \
                                   (__attribute__((address_space(3))) void*)(l), 16, 0, 0)

// ---------- K0: weight conversion + BN folding ----------
// w1s PRE-SWIZZLED with key (o ^ (o>>3)) & 7 on c-bits 3..5 so conv1's linear
// gload_lds dest yields 2-way-max bank conflicts on 32x32 B-frag ds_read_b128.
__global__ __launch_bounds__(256) void prep_kernel(
    const float* __restrict__ w1, const float* __restrict__ w2,
    const float* __restrict__ b1, const float* __restrict__ g1, const float* __restrict__ be1,
    const float* __restrict__ m1, const float* __restrict__ v1,
    const float* __restrict__ b2, const float* __restrict__ g2, const float* __restrict__ be2,
    const float* __restrict__ m2, const float* __restrict__ v2,
    unsigned short* __restrict__ w1s, unsigned short* __restrict__ w2b,
    float* __restrict__ sc1, float* __restrict__ sh1,
    float* __restrict__ sc2, float* __restrict__ sh2)
{
  int i = blockIdx.x * 256 + threadIdx.x;
  int stride = gridDim.x * 256;
  for (int k = i; k < 512 * 2048; k += stride){
    int o = k >> 11, c = k & 2047;
    int key = (o ^ (o >> 3)) & 7;
    w1s[(o << 11) | (c ^ (key << 3))] = f32_to_bf16(w1[k]);
  }
  for (int k = i; k < 256 * 512;  k += stride) w2b[k] = f32_to_bf16(w2[k]);
  if (i < 512){
    float s = g1[i] * rsqrtf(v1[i] + 1e-5f);
    sc1[i] = s;
    sh1[i] = (b1[i] - m1[i]) * s + be1[i];   // conv bias folded into BN shift
  } else if (i - 512 < 256){
    int o = i - 512;
    float s = g2[o] * rsqrtf(v2[o] + 1e-5f);
    sc2[o] = s;
    sh2[o] = (b2[o] - m2[o]) * s + be2[o];
  }
}

// ---------- K1: conv1 full map: Zt[b*4096+p][512] = (W1.F)^T, bf16 ----------
// Tile 64p x 128o, BK=64, grid 1024 = 4 blocks/CU (TLP is the latency-hider),
// 4 waves of 32p x 64o, 32x32x16 MFMA (acc = 2 x f32x16). Single-buffered
// m97-style 2-barrier loop, 24 KB LDS. XCD-chunked ids: the 4 o-tiles of one
// p-panel are co-resident on one XCD -> A-panel served by L2 after first read.
__global__ __launch_bounds__(256, 4) void conv1_kernel(
    const unsigned short* __restrict__ w1s,   // [512][2048] bf16 pre-swizzled
    const float* __restrict__ feat,           // [4][2048][4096] f32
    unsigned short* __restrict__ zt)          // [4*4096][512] bf16
{
  __shared__ unsigned short ldsB[64 * 64];    // feat tile [p][c] swz, 8 KB
  __shared__ unsigned short ldsA[128 * 64];   // weight tile [o][c'] swz, 16 KB
  int t = threadIdx.x, l = t & 63, wid = t >> 6;
  int wp = wid >> 1, wo = wid & 1;            // wave grid 2p x 2o

  int lid = ((blockIdx.x & 7) << 7) | (blockIdx.x >> 3);  // XCD-chunked
  int ot = lid & 3;                 // 4 o-tiles consecutive on same XCD
  int pt = lid >> 2;                // 0..255
  int bb = pt >> 6;
  int p0 = (pt & 63) << 6;
  int o0 = ot << 7;

  // B(feat) staging: thread loads 4 c-rows (c4..c4+3) x f32x4 at p4
  int c4 = (t >> 4) << 2;
  int p4 = (t & 15) << 2;
  const float* fBase = feat + ((size_t)(bb * 2048 + c4)) * 4096 + p0 + p4;

  // A(weights) DMA: 4 x 16B per thread; slot = i*256+t -> o = slot>>3 (i*32 step)
  const unsigned short* aBase = w1s + ((size_t)(o0 + (t >> 3))) * 2048 + (t & 7) * 8;
  unsigned short* aDst = ldsA + (t >> 3) * 64 + (t & 7) * 8;

  f32x16 acc[2];
  #pragma unroll
  for (int n = 0; n < 2; ++n)
    #pragma unroll
    for (int r = 0; r < 16; ++r) acc[n][r] = 0.f;

  f32x4 rb[4];

#define LOAD_B(kt) do {                                                     \
    const float* fp_ = fBase + (size_t)(kt) * 4096;                         \
    rb[0] = *(const f32x4*)(fp_);                                           \
    rb[1] = *(const f32x4*)(fp_ + 4096);                                    \
    rb[2] = *(const f32x4*)(fp_ + 8192);                                    \
    rb[3] = *(const f32x4*)(fp_ + 12288);                                   \
  } while (0)

#define WRITE_B() do {                                                      \
    _Pragma("unroll")                                                       \
    for (int i = 0; i < 4; ++i){                                            \
      int p_ = p4 + i;                                                      \
      int f_ = (p_ ^ (p_ >> 3)) & 7;                                        \
      u32 lo_ = ((u32)f32_to_bf16(rb[0][i])) | (((u32)f32_to_bf16(rb[1][i])) << 16); \
      u32 hi_ = ((u32)f32_to_bf16(rb[2][i])) | (((u32)f32_to_bf16(rb[3][i])) << 16); \
      u64 v_ = ((u64)hi_ << 32) | lo_;                                      \
      *(u64*)((char*)ldsB + p_ * 128 + ((c4 * 2) ^ (f_ << 4))) = v_;        \
    }                                                                       \
  } while (0)

#define DMA_A(kt) do {                                                      \
    _Pragma("unroll")                                                       \
    for (int i = 0; i < 4; ++i)                                             \
      GLOAD_LDS16(aBase + (kt) + (size_t)i * (32 * 2048), aDst + i * (32 * 64)); \
  } while (0)

#define MFMA_ALL() do {                                                     \
    _Pragma("unroll")                                                       \
    for (int ks = 0; ks < 4; ++ks){                                         \
      int cb_ = ks * 32 + (l >> 5) * 16;                                    \
      int p_ = wp * 32 + (l & 31);                                          \
      int fp_ = (p_ ^ (p_ >> 3)) & 7;                                       \
      bf16x8 af_ = *(const bf16x8*)((const char*)ldsB + p_ * 128 + (cb_ ^ (fp_ << 4))); \
      _Pragma("unroll")                                                     \
      for (int n = 0; n < 2; ++n){                                          \
        int o_ = wo * 64 + n * 32 + (l & 31);                               \
        int fo_ = (o_ ^ (o_ >> 3)) & 7;                                     \
        bf16x8 bf_ = *(const bf16x8*)((const char*)ldsA + o_ * 128 + (cb_ ^ (fo_ << 4))); \
        acc[n] = __builtin_amdgcn_mfma_f32_32x32x16_bf16(af_, bf_, acc[n], 0, 0, 0); \
      }                                                                     \
    }                                                                       \
  } while (0)

  LOAD_B(0);
  for (int kt = 0; kt < 2048; kt += 64){
    WRITE_B();                                   // waits rb's loads (compiler vmcnt)
    if (kt < 1984) LOAD_B(kt + 64);              // prefetch next (drained at barrier)
    DMA_A(kt);
    __syncthreads();                             // vmcnt0+lgkm0: tiles ready
    MFMA_ALL();
    asm volatile("s_waitcnt lgkmcnt(0)" ::: "memory");
    __builtin_amdgcn_s_barrier();
  }

  // epilogue: stage [64p][128o] to LDS (reuse ldsA, 16 KB), then coalesced out
  // 32x32 C layout: col=lane&31 (B/o), row=(reg&3)+8*(reg>>2)+4*(lane>>5) (A/p)
  #pragma unroll
  for (int n = 0; n < 2; ++n){
    int o_c = wo * 64 + n * 32 + (l & 31);
    #pragma unroll
    for (int r = 0; r < 16; ++r){
      int p_ = wp * 32 + (r & 3) + 8 * (r >> 2) + 4 * (l >> 5);
      *(unsigned short*)((char*)ldsA + p_ * 256 + ((o_c * 2) ^ ((p_ & 7) << 4))) =
          f32_to_bf16(acc[n][r]);
    }
  }
  __syncthreads();
  {
    int p = t >> 2, seg = t & 3;
    size_t dstb = ((size_t)(bb * 4096 + p0 + p)) * 1024 + (size_t)o0 * 2 + seg * 64;
    int swz = (p & 7) << 4;
    #pragma unroll
    for (int j = 0; j < 4; ++j){
      int y = (seg * 64 + j * 16) ^ swz;
      f32x4 v = *(const f32x4*)((char*)ldsA + p * 256 + y);
      *(f32x4*)((char*)zt + dstb + j * 16) = v;
    }
  }
#undef LOAD_B
#undef WRITE_B
#undef DMA_A
#undef MFMA_ALL
}

// ---------- K2: ROI gather on Zt (512 ch) + BN1 + ReLU -> h1 bf16 [6272][512] ----------
__global__ __launch_bounds__(256) void roi_gather_kernel(
    const unsigned short* __restrict__ zt, const float* __restrict__ boxes,
    const float* __restrict__ sc1, const float* __restrict__ sh1,
    unsigned short* __restrict__ h1)
{
  int ky = blockIdx.x, roi = blockIdx.y;
  __shared__ int   sIdx[16][8];
  __shared__ float sW[16][8];
  int t = threadIdx.x;

  int   b   = (int)boxes[roi * 5 + 0];
  float bx1 = boxes[roi * 5 + 1], by1 = boxes[roi * 5 + 2];
  float bx2 = boxes[roi * 5 + 3], by2 = boxes[roi * 5 + 4];
  float rw = fmaxf(bx2 - bx1, 1.f), rh = fmaxf(by2 - by1, 1.f);
  float bw = rw * (1.f / 7.f), bh = rh * (1.f / 7.f);

  if (t < 28){
    int kx = t >> 2, s = t & 3;
    int sy = s >> 1, sx = s & 1;
    float yy = by1 + ((float)ky + ((float)sy + 0.5f) * 0.5f) * bh;
    float xx = bx1 + ((float)kx + ((float)sx + 0.5f) * 0.5f) * bw;
    bool vy = (yy >= -1.f) && (yy <= 64.f);
    bool vx = (xx >= -1.f) && (xx <= 64.f);
    float yc = fminf(fmaxf(yy, 0.f), 63.f);
    float xc = fminf(fmaxf(xx, 0.f), 63.f);
    int iy0 = (int)yc, ix0 = (int)xc;
    int iy1 = min(iy0 + 1, 63), ix1 = min(ix0 + 1, 63);
    float fy = yc - (float)iy0, fx = xc - (float)ix0;
    float v = (vy && vx) ? 0.25f : 0.f;
    float wy0 = 1.f - fy, wx0 = 1.f - fx;
    sIdx[s * 4 + 0][kx] = iy0 * 64 + ix0;  sW[s * 4 + 0][kx] = wy0 * wx0 * v;
    sIdx[s * 4 + 1][kx] = iy0 * 64 + ix1;  sW[s * 4 + 1][kx] = wy0 * fx  * v;
    sIdx[s * 4 + 2][kx] = iy1 * 64 + ix0;  sW[s * 4 + 2][kx] = fy  * wx0 * v;
    sIdx[s * 4 + 3][kx] = iy1 * 64 + ix1;  sW[s * 4 + 3][kx] = fy  * fx  * v;
  }
  __syncthreads();

  int w = t >> 6, l = t & 63;
  f32x4 s0 = *(const f32x4*)(sc1 + l * 8);
  f32x4 s1 = *(const f32x4*)(sc1 + l * 8 + 4);
  f32x4 h0 = *(const f32x4*)(sh1 + l * 8);
  f32x4 hh = *(const f32x4*)(sh1 + l * 8 + 4);
  const unsigned short* zb = zt + ((size_t)b * 4096) * 512 + l * 8;

  for (int kx = w; kx < 7; kx += 4){
    float a[8];
    #pragma unroll
    for (int j = 0; j < 8; ++j) a[j] = 0.f;
    #pragma unroll
    for (int i = 0; i < 16; ++i){
      int idx = sIdx[i][kx];
      float wt = sW[i][kx];
      u16x8 v = *(const u16x8*)(zb + (size_t)idx * 512);
      #pragma unroll
      for (int j = 0; j < 8; ++j) a[j] += wt * bf16_to_f32(v[j]);
    }
    u16x8 o;
    #pragma unroll
    for (int j = 0; j < 4; ++j){
      float v0 = fmaxf(a[j] * s0[j] + h0[j], 0.f);
      float v1 = fmaxf(a[j + 4] * s1[j] + hh[j], 0.f);
      o[j] = f32_to_bf16(v0);
      o[j + 4] = f32_to_bf16(v1);
    }
    *(u16x8*)(h1 + ((size_t)(roi * 49 + ky * 7 + kx)) * 512 + l * 8) = o;
  }
}

// ---------- K3: bf16 GEMM, B-transposed input, fused scale/shift + ReLU ----------
template<int BM, int BN>
__global__ __launch_bounds__(256) void gemm_bt_relu(
    const unsigned short* __restrict__ A, const unsigned short* __restrict__ Bt,
    const float* __restrict__ scale, const float* __restrict__ shift,
    unsigned short* __restrict__ C, int M, int N, int K)
{
  constexpr int BK = 64;
  constexpr int FM = BM / 32;
  constexpr int FN = BN / 32;
  __shared__ unsigned short lds_a[BM * BK];
  __shared__ unsigned short lds_b[BN * BK];
  int t = threadIdx.x;
  int l = t & 63, wid = t >> 6;
  int wr = wid >> 1, wc = wid & 1;
  int m0 = blockIdx.y * BM, n0 = blockIdx.x * BN;

  f32x4 acc[FM][FN];
  f32x4 z = {0.f, 0.f, 0.f, 0.f};
  #pragma unroll
  for (int m = 0; m < FM; ++m)
    #pragma unroll
    for (int n = 0; n < FN; ++n) acc[m][n] = z;

  const unsigned short* Ab = A  + (size_t)m0 * K;
  const unsigned short* Bb = Bt + (size_t)n0 * K;

  for (int kt = 0; kt < K; kt += BK){
    #pragma unroll
    for (int r = 0; r < BM / 32; ++r){
      int row = r * 32 + (t >> 3);
      GLOAD_LDS16(Ab + (size_t)row * K + kt + (t & 7) * 8,
                  lds_a + row * BK + (t & 7) * 8);
    }
    #pragma unroll
    for (int r = 0; r < BN / 32; ++r){
      int row = r * 32 + (t >> 3);
      GLOAD_LDS16(Bb + (size_t)row * K + kt + (t & 7) * 8,
                  lds_b + row * BK + (t & 7) * 8);
    }
    __syncthreads();
    #pragma unroll
    for (int ks = 0; ks < 2; ++ks){
      bf16x8 af[FM], bfr[FN];
      #pragma unroll
      for (int m = 0; m < FM; ++m)
        af[m] = *reinterpret_cast<const bf16x8*>(
            lds_a + (wr * (BM / 2) + m * 16 + (l & 15)) * BK + ks * 32 + (l >> 4) * 8);
      #pragma unroll
      for (int n = 0; n < FN; ++n)
        bfr[n] = *reinterpret_cast<const bf16x8*>(
            lds_b + (wc * (BN / 2) + n * 16 + (l & 15)) * BK + ks * 32 + (l >> 4) * 8);
      #pragma unroll
      for (int m = 0; m < FM; ++m)
        #pragma unroll
        for (int n = 0; n < FN; ++n)
          acc[m][n] = __builtin_amdgcn_mfma_f32_16x16x32_bf16(af[m], bfr[n], acc[m][n], 0, 0, 0);
    }
    __syncthreads();
  }

  #pragma unroll
  for (int m = 0; m < FM; ++m){
    int gr = m0 + wr * (BM / 2) + m * 16 + (l >> 4) * 4;
    #pragma unroll
    for (int n = 0; n < FN; ++n){
      int gc = n0 + wc * (BN / 2) + n * 16 + (l & 15);
      float sc = scale[gc], sh = shift[gc];
      #pragma unroll
      for (int r = 0; r < 4; ++r){
        float v = acc[m][n][r] * sc + sh;
        v = fmaxf(v, 0.f);
        C[(size_t)(gr + r) * N + gc] = f32_to_bf16(v);
      }
    }
  }
}

// ---------- K4: mean over 49 bins -> out f32 [128][256] ----------
__global__ __launch_bounds__(256) void reduce_kernel(
    const unsigned short* __restrict__ h2, float* __restrict__ out)
{
  int n = blockIdx.x, o = threadIdx.x;
  const unsigned short* p = h2 + (size_t)n * 49 * 256 + o;
  float s = 0.f;
  for (int j = 0; j < 49; ++j) s += bf16_to_f32(p[j * 256]);
  out[n * 256 + o] = s * (1.f / 49.f);
}

// ---------- launch ----------
extern "C" void kernel_launch(void* const* d_in, const int* in_sizes, int n_in,
                              void* d_out, int out_size, void* d_ws, size_t ws_size,
                              hipStream_t stream)
{
  const float* feat  = (const float*)d_in[0];
  const float* boxes = (const float*)d_in[1];
  const float* w1  = (const float*)d_in[2];
  const float* b1  = (const float*)d_in[3];
  const float* g1  = (const float*)d_in[4];
  const float* be1 = (const float*)d_in[5];
  const float* m1  = (const float*)d_in[6];
  const float* v1  = (const float*)d_in[7];
  const float* w2  = (const float*)d_in[8];
  const float* b2  = (const float*)d_in[9];
  const float* g2  = (const float*)d_in[10];
  const float* be2 = (const float*)d_in[11];
  const float* m2  = (const float*)d_in[12];
  const float* v2  = (const float*)d_in[13];
  float* out = (float*)d_out;

  char* ws = (char*)d_ws;
  unsigned short* w1s = (unsigned short*)(ws);                         // 2 MB (pre-swizzled)
  unsigned short* w2b = (unsigned short*)(ws + (2u << 20));            // 256 KB
  float* sc1 = (float*)(ws + (2u << 20) + (256u << 10));
  float* sh1 = sc1 + 512;
  float* sc2 = sh1 + 512;
  float* sh2 = sc2 + 256;
  unsigned short* zt = (unsigned short*)(ws + (4u  << 20));            // 16.8 MB
  unsigned short* h1 = (unsigned short*)(ws + (24u << 20));            // 6.4 MB
  unsigned short* h2 = (unsigned short*)(ws + (32u << 20));            // 3.2 MB

  hipLaunchKernelGGL(prep_kernel, dim3(256), dim3(256), 0, stream,
                     w1, w2, b1, g1, be1, m1, v1, b2, g2, be2, m2, v2,
                     w1s, w2b, sc1, sh1, sc2, sh2);
  hipLaunchKernelGGL(conv1_kernel, dim3(1024), dim3(256), 0, stream,
                     w1s, feat, zt);
  hipLaunchKernelGGL(roi_gather_kernel, dim3(7, 128), dim3(256), 0, stream,
                     zt, boxes, sc1, sh1, h1);
  hipLaunchKernelGGL(HIP_KERNEL_NAME(gemm_bt_relu<64, 64>),
                     dim3(256 / 64, 6272 / 64), dim3(256), 0, stream,
                     h1, w2b, sc2, sh2, h2, 6272, 256, 512);
  hipLaunchKernelGGL(reduce_kernel, dim3(128), dim3(256), 0, stream, h2, out);
}